// Round 7
// baseline (314.083 us; speedup 1.0000x reference)
//
#include <hip/hip_runtime.h>

typedef __bf16 bf16;
typedef __attribute__((ext_vector_type(8))) __bf16 bf16x8;
typedef __attribute__((ext_vector_type(4))) __bf16 bf16x4;
typedef __attribute__((ext_vector_type(4))) float f32x4;

#define GLDS16(g, l) __builtin_amdgcn_global_load_lds( \
    (const __attribute__((address_space(1))) void*)(g), \
    (__attribute__((address_space(3))) void*)(l), 16, 0, 0)

#define MFMA16(a, b, c) __builtin_amdgcn_mfma_f32_16x16x32_bf16(a, b, c, 0, 0, 0)

// ds_read_b64_tr_b16: per-lane gather of 4 bf16 at 32B stride (HW transpose read)
#define TR16(dst, addr, off) \
  asm volatile("ds_read_b64_tr_b16 %0, %1 offset:" #off : "=v"(dst) : "v"(addr))

// ---------------------------------------------------------------- convert
struct CvtArgs { const float* in[4]; bf16* out[4]; };

__global__ __launch_bounds__(256) void f2b_multi(CvtArgs a, int n8) {
  int i = blockIdx.x * 256 + threadIdx.x;
  if (i >= n8) return;
  const float* in = a.in[blockIdx.y];
  bf16* out = a.out[blockIdx.y];
  const f32x4* p = (const f32x4*)in + (size_t)i * 2;
  f32x4 x = p[0], y = p[1];
  bf16x8 o;
  o[0] = (bf16)x[0]; o[1] = (bf16)x[1]; o[2] = (bf16)x[2]; o[3] = (bf16)x[3];
  o[4] = (bf16)y[0]; o[5] = (bf16)y[1]; o[6] = (bf16)y[2]; o[7] = (bf16)y[3];
  ((bf16x8*)out)[i] = o;
}

// ---------------------------------------------------------------- GEMM body v6
// C[m,n] = sum_k A[m,k] * Bw[n,k]  (+bias[n])
// 256x256 tile (staged-byte intensity 128 vs 64 for 128^2 -- the binding
// constraint is L2->CU staging delivery ~22B/cyc/CU), BK=32, 512 thr = 8
// waves (2 row-slabs x 4 col-slabs), per-wave 128x64 (acc 8x4).
// Proven 1-barrier-per-kstep double-buffer structure.
// EPI==0: store bf16 C (+bias).  EPI==1: aout[m] += sum_n tanh(C+bias)*qv[n].
template <int EPI>
__device__ __forceinline__ void gemm_body(
    const bf16* __restrict__ A, const bf16* __restrict__ Bw,
    const float* __restrict__ bias, const float* __restrict__ qv,
    bf16* __restrict__ C, float* __restrict__ aout, const int N, const int K) {
  __shared__ __attribute__((aligned(16))) bf16 As[2][8192];  // [k/8][256][8]
  __shared__ __attribute__((aligned(16))) bf16 Bs[2][8192];
  const int tid = threadIdx.x;
  const int wid = tid >> 6, lane = tid & 63;
  const int g = lane >> 4, lc = lane & 15;
  const int row0 = blockIdx.x * 256, col0 = blockIdx.y * 256;
  const int wr = wid >> 2, wc = wid & 3;  // 2 row-slabs x 4 col-slabs

  // staging: slot s = chunk*256 + row; thread handles slots tid and tid+512
  const int s0 = tid, s1 = tid + 512;
  const bf16* gA0 = A + ((size_t)(row0 + (s0 & 255)) * K + (s0 >> 8) * 8);
  const bf16* gA1 = A + ((size_t)(row0 + (s1 & 255)) * K + (s1 >> 8) * 8);
  const bf16* gB0 = Bw + ((size_t)(col0 + (s0 & 255)) * K + (s0 >> 8) * 8);
  const bf16* gB1 = Bw + ((size_t)(col0 + (s1 & 255)) * K + (s1 >> 8) * 8);
  const int dA0 = (s0 - lane) * 8, dA1 = (s1 - lane) * 8;  // wave-uniform dests

  const f32x4 z4 = {0.f, 0.f, 0.f, 0.f};
  f32x4 acc[8][4];
#pragma unroll
  for (int m = 0; m < 8; ++m)
#pragma unroll
    for (int n = 0; n < 4; ++n) acc[m][n] = z4;

  // prologue: stage k-tile 0 into buffer 0
  GLDS16(gA0, &As[0][dA0]);
  GLDS16(gA1, &As[0][dA1]);
  GLDS16(gB0, &Bs[0][dA0]);
  GLDS16(gB1, &Bs[0][dA1]);

  for (int kt = 0; kt < K; kt += 32) {
    __syncthreads();  // implicit vmcnt(0): tile kt landed; separates prev
                      // iteration's reads from next tile's writes
    const int cur = (kt >> 5) & 1;
    if (kt + 32 < K) {
      const int nb = cur ^ 1;
      GLDS16(gA0 + kt + 32, &As[nb][dA0]);
      GLDS16(gA1 + kt + 32, &As[nb][dA1]);
      GLDS16(gB0 + kt + 32, &Bs[nb][dA0]);
      GLDS16(gB1 + kt + 32, &Bs[nb][dA1]);
    }
    bf16x8 af[8], bfv[4];
#pragma unroll
    for (int m = 0; m < 8; ++m)
      af[m] = *(const bf16x8*)(&As[cur][g * 2048 + (wr * 128 + m * 16 + lc) * 8]);
#pragma unroll
    for (int n = 0; n < 4; ++n)
      bfv[n] = *(const bf16x8*)(&Bs[cur][g * 2048 + (wc * 64 + n * 16 + lc) * 8]);
#pragma unroll
    for (int m = 0; m < 8; ++m)
#pragma unroll
      for (int n = 0; n < 4; ++n)
        acc[m][n] = MFMA16(af[m], bfv[n], acc[m][n]);
  }

  if constexpr (EPI == 0) {
#pragma unroll
    for (int n = 0; n < 4; ++n) {
      const int col = col0 + wc * 64 + n * 16 + lc;
      const float bb = bias[col];
#pragma unroll
      for (int m = 0; m < 8; ++m)
#pragma unroll
        for (int r = 0; r < 4; ++r) {
          const int row = row0 + wr * 128 + m * 16 + g * 4 + r;
          C[(size_t)row * N + col] = (bf16)(acc[m][n][r] + bb);
        }
    }
  } else {
    float part[8][4];
#pragma unroll
    for (int m = 0; m < 8; ++m)
#pragma unroll
      for (int r = 0; r < 4; ++r) part[m][r] = 0.f;
#pragma unroll
    for (int n = 0; n < 4; ++n) {
      const int col = col0 + wc * 64 + n * 16 + lc;
      const float bb = bias[col];
      const float qq = qv[col];
#pragma unroll
      for (int m = 0; m < 8; ++m)
#pragma unroll
        for (int r = 0; r < 4; ++r)
          part[m][r] += tanhf(acc[m][n][r] + bb) * qq;
    }
#pragma unroll
    for (int m = 0; m < 8; ++m)
#pragma unroll
      for (int r = 0; r < 4; ++r) {
        float v = part[m][r];
        v += __shfl_xor(v, 1); v += __shfl_xor(v, 2);
        v += __shfl_xor(v, 4); v += __shfl_xor(v, 8);
        if (lc == 0) {
          const int row = row0 + wr * 128 + m * 16 + g * 4 + r;
          atomicAdd(&aout[row], v);
        }
      }
  }
}

struct GemmSet { const bf16* A; const bf16* Bw; const float* bias; bf16* C; };
struct Gemm3Args { GemmSet s[3]; };

__global__ __launch_bounds__(512, 2) void gemm3_kernel(Gemm3Args a) {
  const GemmSet s = a.s[blockIdx.z];
  gemm_body<0>(s.A, s.Bw, s.bias, nullptr, s.C, nullptr, 1024, 1024);
}

__global__ __launch_bounds__(512, 2) void gemm_a_kernel(
    const bf16* __restrict__ A, const bf16* __restrict__ Bw,
    const float* __restrict__ bias, const float* __restrict__ qv,
    float* __restrict__ aout) {
  gemm_body<1>(A, Bw, bias, qv, nullptr, aout, 1024, 1024);
}

// ---------------------------------------------------------------- attention v3
// Swapped QK^T (lane-local softmax), double-buffered K/V staging with a single
// barrier per KV tile, defer-rescale (THR=8), setprio around MFMA clusters.
// grid: (B*H, S/64). 4 waves x 16 q-rows each. KV tiles of 64.
__global__ __launch_bounds__(256) void attn_kernel(
    const bf16* __restrict__ qp, const bf16* __restrict__ kp,
    const bf16* __restrict__ vp, bf16* __restrict__ xb, float* __restrict__ xf) {
  constexpr int S = 1024, D = 1024;
  __shared__ __attribute__((aligned(16))) bf16 Ks[8192];  // 2x [d/8][64 kv][8]
  __shared__ __attribute__((aligned(16))) bf16 Vs[8192];  // 2x [kv/4][d/16][4][16]
  __shared__ __attribute__((aligned(16))) bf16 Ps[4096];  // per-wave [16 q][64 kv swz]
  const int tid = threadIdx.x, wid = tid >> 6, lane = tid & 63;
  const int g = lane >> 4, lc = lane & 15;
  const int b = blockIdx.x >> 4, h = blockIdx.x & 15;
  const int q0 = blockIdx.y * 64;
  const size_t base = (size_t)b * S * D + (size_t)h * 64;

  // Q fragments, pre-scaled by 1/sqrt(DK)=0.125 (exact in bf16)
  bf16x8 qf[2];
  {
    const bf16* qrow = qp + base + (size_t)(q0 + wid * 16 + lc) * D;
    qf[0] = *(const bf16x8*)(qrow + g * 8);
    qf[1] = *(const bf16x8*)(qrow + 32 + g * 8);
#pragma unroll
    for (int j = 0; j < 8; ++j) {
      qf[0][j] = (bf16)((float)qf[0][j] * 0.125f);
      qf[1][j] = (bf16)((float)qf[1][j] * 0.125f);
    }
  }
  float m_s = -1e30f, l_s = 0.f;
  const f32x4 z4 = {0.f, 0.f, 0.f, 0.f};
  f32x4 ax[4];  // O^T: ax[m][r] = O[q=lc][d=16m+4g+r]
#pragma unroll
  for (int m = 0; m < 4; ++m) ax[m] = z4;

  // K staging (chunked [d/8][64][8]): linear dest, linear source
  const int c0 = tid, c1 = tid + 256;
  const bf16* gK0 = kp + base + (size_t)(c0 & 63) * D + (c0 >> 6) * 8;
  const bf16* gK1 = kp + base + (size_t)(c1 & 63) * D + (c1 >> 6) * 8;
  bf16* lK0 = Ks + (size_t)(c0 - lane) * 8;
  bf16* lK1 = Ks + (size_t)(c1 - lane) * 8;
  // V staging: linear LDS dest = subtile slot E8; global source pre-swizzled
  const bf16* gV0 = vp + base + (size_t)((c0 >> 5) * 4 + ((c0 >> 1) & 3)) * D +
                    ((c0 >> 3) & 3) * 16 + (c0 & 1) * 8;
  const bf16* gV1 = vp + base + (size_t)((c1 >> 5) * 4 + ((c1 >> 1) & 3)) * D +
                    ((c1 >> 3) & 3) * 16 + (c1 & 1) * 8;
  bf16* lV0 = Vs + (size_t)(c0 - lane) * 8;
  bf16* lV1 = Vs + (size_t)(c1 - lane) * 8;

  bf16* pw = Ps + wid * 1024;
  const int pswz_a = lc & 3, pswz_b = (lc >> 2) & 3;
  const unsigned vaddr0 =
      (unsigned)(uintptr_t)(const __attribute__((address_space(3))) bf16*)(Vs + 512 * g + 4 * lc);

  // prologue: stage KV tile 0 into buffer 0
  GLDS16(gK0, lK0);
  GLDS16(gK1, lK1);
  GLDS16(gV0, lV0);
  GLDS16(gV1, lV1);

  for (int t = 0; t < 16; ++t) {
    __syncthreads();  // implicit vmcnt(0): tile t's loads landed (prefetched a
                      // full tile ago); separates t-1 reads from t+1 writes
    const int cur = t & 1;
    if (t < 15) {
      const size_t off = (size_t)(t + 1) * 64 * D;
      const int nb = cur ^ 1;
      GLDS16(gK0 + off, lK0 + nb * 4096);
      GLDS16(gK1 + off, lK1 + nb * 4096);
      GLDS16(gV0 + off, lV0 + nb * 4096);
      GLDS16(gV1 + off, lV1 + nb * 4096);
    }
    const bf16* Kb = Ks + cur * 4096;
    const unsigned va = vaddr0 + cur * 8192u;

    // S^T = K Q^T: sc[m][r] = S[q=lc][kv=16m+4g+r] (scale folded into qf)
    f32x4 sc[4];
    __builtin_amdgcn_s_setprio(1);
#pragma unroll
    for (int m = 0; m < 4; ++m) {
      f32x4 z = z4;
      bf16x8 kf0 = *(const bf16x8*)(Kb + (size_t)g * 512 + (m * 16 + lc) * 8);
      bf16x8 kf1 = *(const bf16x8*)(Kb + (size_t)(4 + g) * 512 + (m * 16 + lc) * 8);
      z = MFMA16(kf0, qf[0], z);
      z = MFMA16(kf1, qf[1], z);
      sc[m] = z;
    }
    __builtin_amdgcn_s_setprio(0);

    // online softmax with defer-rescale (THR=8)
    float mx = -1e30f;
#pragma unroll
    for (int m = 0; m < 4; ++m)
      mx = fmaxf(mx, fmaxf(fmaxf(sc[m][0], sc[m][1]), fmaxf(sc[m][2], sc[m][3])));
    mx = fmaxf(mx, __shfl_xor(mx, 16));
    mx = fmaxf(mx, __shfl_xor(mx, 32));
    if (!__all(mx - m_s <= 8.f)) {
      const float mn = fmaxf(m_s, mx);
      const float cr = __expf(m_s - mn);
      l_s *= cr;
#pragma unroll
      for (int m = 0; m < 4; ++m) ax[m] *= cr;
      m_s = mn;
    }
    float sm = 0.f;
#pragma unroll
    for (int m = 0; m < 4; ++m)
#pragma unroll
      for (int r = 0; r < 4; ++r) {
        float p = __expf(sc[m][r] - m_s);
        sc[m][r] = p;
        sm += p;
      }
    sm += __shfl_xor(sm, 16);
    sm += __shfl_xor(sm, 32);
    l_s += sm;

    // P -> bf16, packed b64 writes into swizzled per-wave buffer
#pragma unroll
    for (int m = 0; m < 4; ++m) {
      bf16x4 pk;
      pk[0] = (bf16)sc[m][0]; pk[1] = (bf16)sc[m][1];
      pk[2] = (bf16)sc[m][2]; pk[3] = (bf16)sc[m][3];
      *(bf16x4*)(pw + lc * 64 + 16 * (m ^ pswz_a) + 4 * (g ^ pswz_b)) = pk;
    }

    // P fragments (B operand): lane needs P[q=lc][kv=32kk+8g+4jh+r]
    bf16x4 pr[2][2];
#pragma unroll
    for (int kk = 0; kk < 2; ++kk)
#pragma unroll
      for (int jh = 0; jh < 2; ++jh) {
        const int msrc = 2 * kk + (g >> 1);
        const int gsrc = (2 * g + jh) & 3;
        pr[kk][jh] = *(const bf16x4*)(pw + lc * 64 + 16 * (msrc ^ pswz_a) + 4 * (gsrc ^ pswz_b));
      }
    bf16x8 pf0 = __builtin_shufflevector(pr[0][0], pr[0][1], 0, 1, 2, 3, 4, 5, 6, 7);
    bf16x8 pf1 = __builtin_shufflevector(pr[1][0], pr[1][1], 0, 1, 2, 3, 4, 5, 6, 7);

    // V^T fragments (A operand) via HW transpose reads
    bf16x4 vt[4][2][2];  // [md][kk][jh]
    TR16(vt[0][0][0], va, 0);    TR16(vt[1][0][0], va, 128);
    TR16(vt[2][0][0], va, 256);  TR16(vt[3][0][0], va, 384);
    TR16(vt[0][0][1], va, 512);  TR16(vt[1][0][1], va, 640);
    TR16(vt[2][0][1], va, 768);  TR16(vt[3][0][1], va, 896);
    TR16(vt[0][1][0], va, 4096); TR16(vt[1][1][0], va, 4224);
    TR16(vt[2][1][0], va, 4352); TR16(vt[3][1][0], va, 4480);
    TR16(vt[0][1][1], va, 4608); TR16(vt[1][1][1], va, 4736);
    TR16(vt[2][1][1], va, 4864); TR16(vt[3][1][1], va, 4992);
    asm volatile("s_waitcnt lgkmcnt(0)" ::: "memory");
    __builtin_amdgcn_sched_barrier(0);

    // O^T += V^T P^T
    __builtin_amdgcn_s_setprio(1);
#pragma unroll
    for (int md = 0; md < 4; ++md) {
      bf16x8 a0 = __builtin_shufflevector(vt[md][0][0], vt[md][0][1], 0, 1, 2, 3, 4, 5, 6, 7);
      bf16x8 a1 = __builtin_shufflevector(vt[md][1][0], vt[md][1][1], 0, 1, 2, 3, 4, 5, 6, 7);
      ax[md] = MFMA16(a0, pf0, ax[md]);
      ax[md] = MFMA16(a1, pf1, ax[md]);
    }
    __builtin_amdgcn_s_setprio(0);
  }

  // normalize + store x (bf16 for Wa-GEMM, f32 for final pooling), packed
  const float inv = 1.0f / l_s;
  const int qrow = q0 + wid * 16 + lc;
  float* xfr = xf + base + (size_t)qrow * D;
  bf16* xbr = xb + base + (size_t)qrow * D;
#pragma unroll
  for (int m = 0; m < 4; ++m) {
    f32x4 vv = ax[m] * inv;
    *(f32x4*)(xfr + 16 * m + 4 * g) = vv;
    bf16x4 bb;
    bb[0] = (bf16)vv[0]; bb[1] = (bf16)vv[1];
    bb[2] = (bf16)vv[2]; bb[3] = (bf16)vv[3];
    *(bf16x4*)(xbr + 16 * m + 4 * g) = bb;
  }
}

// ---------------------------------------------------------------- alpha softmax
__global__ __launch_bounds__(256) void softmax_rows(const float* __restrict__ av,
                                                    float* __restrict__ alpha) {
  const int b = blockIdx.x, t = threadIdx.x;
  __shared__ float red[8];
  f32x4 v = *(const f32x4*)(av + b * 1024 + t * 4);
  float m = fmaxf(fmaxf(v[0], v[1]), fmaxf(v[2], v[3]));
#pragma unroll
  for (int o = 1; o < 64; o <<= 1) m = fmaxf(m, __shfl_xor(m, o));
  if ((t & 63) == 0) red[t >> 6] = m;
  __syncthreads();
  m = fmaxf(fmaxf(red[0], red[1]), fmaxf(red[2], red[3]));
  f32x4 e;
  float s = 0.f;
#pragma unroll
  for (int j = 0; j < 4; ++j) { e[j] = __expf(v[j] - m); s += e[j]; }
#pragma unroll
  for (int o = 1; o < 64; o <<= 1) s += __shfl_xor(s, o);
  if ((t & 63) == 0) red[4 + (t >> 6)] = s;
  __syncthreads();
  const float inv = 1.0f / (red[4] + red[5] + red[6] + red[7]);
  *(f32x4*)(alpha + b * 1024 + t * 4) = e * inv;
}

// ---------------------------------------------------------------- pooling
__global__ __launch_bounds__(256) void pool_kernel(const float* __restrict__ xf,
                                                   const float* __restrict__ alpha,
                                                   float* __restrict__ out) {
  const int b = blockIdx.y, sc = blockIdx.x, t = threadIdx.x;
  f32x4 acc = {0.f, 0.f, 0.f, 0.f};
  const float* xrow = xf + (size_t)b * 1024 * 1024;
  for (int s = sc * 64; s < sc * 64 + 64; ++s) {
    const float al = alpha[b * 1024 + s];
    f32x4 xv = *(const f32x4*)(xrow + (size_t)s * 1024 + t * 4);
    acc += xv * al;
  }
  atomicAdd(&out[b * 1024 + t * 4 + 0], acc[0]);
  atomicAdd(&out[b * 1024 + t * 4 + 1], acc[1]);
  atomicAdd(&out[b * 1024 + t * 4 + 2], acc[2]);
  atomicAdd(&out[b * 1024 + t * 4 + 3], acc[3]);
}

// ---------------------------------------------------------------- launch
extern "C" void kernel_launch(void* const* d_in, const int* in_sizes, int n_in,
                              void* d_out, int out_size, void* d_ws, size_t ws_size,
                              hipStream_t stream) {
  const float* Q   = (const float*)d_in[0];
  const float* K   = (const float*)d_in[1];
  const float* V   = (const float*)d_in[2];
  const float* Wq  = (const float*)d_in[3];
  const float* bq  = (const float*)d_in[4];
  const float* Wk  = (const float*)d_in[5];
  const float* bk  = (const float*)d_in[6];
  const float* Wv  = (const float*)d_in[7];
  const float* bv  = (const float*)d_in[8];
  const float* Wa  = (const float*)d_in[9];
  const float* ba  = (const float*)d_in[10];
  const float* qvec = (const float*)d_in[11];
  float* out = (float*)d_out;
  char* ws = (char*)d_ws;
  const size_t MB = 1ull << 20;

  bf16* Wqb = (bf16*)(ws + 0 * MB);
  bf16* Wkb = (bf16*)(ws + 2 * MB);
  bf16* Wvb = (bf16*)(ws + 4 * MB);
  bf16* Wab = (bf16*)(ws + 6 * MB);
  bf16* qb  = (bf16*)(ws + 8 * MB);
  bf16* kb  = (bf16*)(ws + 24 * MB);
  bf16* vb  = (bf16*)(ws + 40 * MB);
  bf16* qp  = (bf16*)(ws + 56 * MB);
  bf16* kp  = (bf16*)(ws + 72 * MB);
  bf16* vp  = (bf16*)(ws + 88 * MB);
  float* av    = (float*)(ws + 104 * MB);
  float* alpha = (float*)(ws + 104 * MB + 65536);
  bf16* xb  = qb;                       // qb dead after Q projection
  float* xf = (float*)(ws + 24 * MB);   // kb+vb dead after K/V projections

  // accumulator zeroing up front
  hipMemsetAsync(av, 0, 8192 * sizeof(float), stream);
  hipMemsetAsync(out, 0, 8192 * sizeof(float), stream);

  // f32 -> bf16 conversions: 2 fused dispatches
  CvtArgs cq = {{Q, K, V, nullptr}, {qb, kb, vb, nullptr}};
  f2b_multi<<<dim3(4096, 3), 256, 0, stream>>>(cq, 1048576);
  CvtArgs cw = {{Wq, Wk, Wv, Wa}, {Wqb, Wkb, Wvb, Wab}};
  f2b_multi<<<dim3(512, 4), 256, 0, stream>>>(cw, 131072);

  // projections: one dispatch, z = {q,k,v}; 256^2 tiles -> 32x4x3 blocks
  Gemm3Args g3 = {{{qb, Wqb, bq, qp}, {kb, Wkb, bk, kp}, {vb, Wvb, bv, vp}}};
  gemm3_kernel<<<dim3(32, 4, 3), 512, 0, stream>>>(g3);

  // flash attention
  attn_kernel<<<dim3(128, 16), 256, 0, stream>>>(qp, kp, vp, xb, xf);

  // pooling head: a[m] = sum_n tanh(x Wa^T + ba)*qvec
  gemm_a_kernel<<<dim3(32, 4), 512, 0, stream>>>(xb, Wab, ba, qvec, av);

  softmax_rows<<<8, 256, 0, stream>>>(av, alpha);
  pool_kernel<<<dim3(16, 8), 256, 0, stream>>>(xf, alpha, out);
}

// Round 8
// 260.000 us; speedup vs baseline: 1.2080x; 1.2080x over previous
//
#include <hip/hip_runtime.h>

typedef __bf16 bf16;
typedef __attribute__((ext_vector_type(8))) __bf16 bf16x8;
typedef __attribute__((ext_vector_type(4))) __bf16 bf16x4;
typedef __attribute__((ext_vector_type(4))) float f32x4;

#define GLDS16(g, l) __builtin_amdgcn_global_load_lds( \
    (const __attribute__((address_space(1))) void*)(g), \
    (__attribute__((address_space(3))) void*)(l), 16, 0, 0)

#define MFMA16(a, b, c) __builtin_amdgcn_mfma_f32_16x16x32_bf16(a, b, c, 0, 0, 0)

// ds_read_b64_tr_b16: per-lane gather of 4 bf16 at 32B stride (HW transpose read)
#define TR16(dst, addr, off) \
  asm volatile("ds_read_b64_tr_b16 %0, %1 offset:" #off : "=v"(dst) : "v"(addr))

// ---------------------------------------------------------------- convert
struct CvtArgs { const float* in[4]; bf16* out[4]; };

__global__ __launch_bounds__(256) void f2b_multi(CvtArgs a, int n8) {
  int i = blockIdx.x * 256 + threadIdx.x;
  if (i >= n8) return;
  const float* in = a.in[blockIdx.y];
  bf16* out = a.out[blockIdx.y];
  const f32x4* p = (const f32x4*)in + (size_t)i * 2;
  f32x4 x = p[0], y = p[1];
  bf16x8 o;
  o[0] = (bf16)x[0]; o[1] = (bf16)x[1]; o[2] = (bf16)x[2]; o[3] = (bf16)x[3];
  o[4] = (bf16)y[0]; o[5] = (bf16)y[1]; o[6] = (bf16)y[2]; o[7] = (bf16)y[3];
  ((bf16x8*)out)[i] = o;
}

// ---------------------------------------------------------------- GEMM body (R4 structure)
// C[m,n] = sum_k A[m,k] * Bw[n,k]  (+bias[n])
// 128x128 block, 512 threads = 8 waves each owning 32x64. Double-buffered
// LDS, 1 barrier per k-step. row0/col0 come from the XCD-chunked swizzle:
// XCD k owns rows [8k,8k+8) x all 8 col-panels -> L2 working set = 8 A-panels
// (2MB) + full B (2MB) = 4MB = one XCD L2. A hits L2 for all 8 consumers.
template <int EPI>
__device__ __forceinline__ void gemm_body(
    const bf16* __restrict__ A, const bf16* __restrict__ Bw,
    const float* __restrict__ bias, const float* __restrict__ qv,
    bf16* __restrict__ C, float* __restrict__ aout,
    const int row0, const int col0, const int N, const int K) {
  __shared__ __attribute__((aligned(16))) bf16 As[8192];  // 2 x [4][128][8]
  __shared__ __attribute__((aligned(16))) bf16 Bs[8192];
  const int tid = threadIdx.x;
  const int wid = tid >> 6, lane = tid & 63;
  const int g = lane >> 4, lc = lane & 15;
  const int wr = wid >> 1, wc = wid & 1;  // 4 row-slabs x 2 col-slabs

  // staging: thread t loads A slot t and B slot t (chunk = t>>7, row = t&127)
  const bf16* gA0 = A + ((size_t)(row0 + (tid & 127)) * K + (tid >> 7) * 8);
  const bf16* gB0 = Bw + ((size_t)(col0 + (tid & 127)) * K + (tid >> 7) * 8);
  bf16* lA0 = As + (size_t)tid * 8;
  bf16* lB0 = Bs + (size_t)tid * 8;

  const f32x4 z4 = {0.f, 0.f, 0.f, 0.f};
  f32x4 acc[2][4];
#pragma unroll
  for (int m = 0; m < 2; ++m)
#pragma unroll
    for (int n = 0; n < 4; ++n) acc[m][n] = z4;

  // prologue: stage k-tile 0 into buffer 0
  GLDS16(gA0, lA0);
  GLDS16(gB0, lB0);

  for (int kt = 0; kt < K; kt += 32) {
    __syncthreads();  // implicit vmcnt(0): this k-tile's loads landed; separates
                      // prev tile's reads from next tile's writes
    const int cur = (kt >> 5) & 1;
    if (kt + 32 < K) {
      const int nb = cur ^ 1;
      GLDS16(gA0 + kt + 32, lA0 + nb * 4096);
      GLDS16(gB0 + kt + 32, lB0 + nb * 4096);
    }
    const bf16* Ab = As + cur * 4096;
    const bf16* Bb = Bs + cur * 4096;
    bf16x8 af[2], bfv[4];
#pragma unroll
    for (int m = 0; m < 2; ++m)
      af[m] = *(const bf16x8*)(Ab + g * 1024 + (wr * 32 + m * 16 + lc) * 8);
#pragma unroll
    for (int n = 0; n < 4; ++n)
      bfv[n] = *(const bf16x8*)(Bb + g * 1024 + (wc * 64 + n * 16 + lc) * 8);
#pragma unroll
    for (int m = 0; m < 2; ++m)
#pragma unroll
      for (int n = 0; n < 4; ++n)
        acc[m][n] = MFMA16(af[m], bfv[n], acc[m][n]);
  }

  if constexpr (EPI == 0) {
#pragma unroll
    for (int n = 0; n < 4; ++n) {
      const int col = col0 + wc * 64 + n * 16 + lc;
      const float bb = bias[col];
#pragma unroll
      for (int m = 0; m < 2; ++m)
#pragma unroll
        for (int r = 0; r < 4; ++r) {
          const int row = row0 + wr * 32 + m * 16 + g * 4 + r;
          C[(size_t)row * N + col] = (bf16)(acc[m][n][r] + bb);
        }
    }
  } else {
    float part[2][4];
#pragma unroll
    for (int m = 0; m < 2; ++m)
#pragma unroll
      for (int r = 0; r < 4; ++r) part[m][r] = 0.f;
#pragma unroll
    for (int n = 0; n < 4; ++n) {
      const int col = col0 + wc * 64 + n * 16 + lc;
      const float bb = bias[col];
      const float qq = qv[col];
#pragma unroll
      for (int m = 0; m < 2; ++m)
#pragma unroll
        for (int r = 0; r < 4; ++r)
          part[m][r] += tanhf(acc[m][n][r] + bb) * qq;
    }
#pragma unroll
    for (int m = 0; m < 2; ++m)
#pragma unroll
      for (int r = 0; r < 4; ++r) {
        float v = part[m][r];
        v += __shfl_xor(v, 1); v += __shfl_xor(v, 2);
        v += __shfl_xor(v, 4); v += __shfl_xor(v, 8);
        if (lc == 0) {
          const int row = row0 + wr * 32 + m * 16 + g * 4 + r;
          atomicAdd(&aout[row], v);
        }
      }
  }
}

// XCD-chunked swizzle for 512 blocks (64 row-panels x 8 col-panels):
// physical p -> logical lg = (p&7)*64 + (p>>3); row = lg>>3, col = lg&7.
// Assuming round-robin physical->XCD, XCD k gets logical [64k, 64k+64) =
// rows [8k,8k+8) col-fast. Bijective since 512 % 8 == 0.
__device__ __forceinline__ void swz512(int phys, int& row0, int& col0) {
  const int lg = (phys & 7) * 64 + (phys >> 3);
  row0 = (lg >> 3) * 128;
  col0 = (lg & 7) * 128;
}

struct GemmSet { const bf16* A; const bf16* Bw; const float* bias; bf16* C; };
struct Gemm3Args { GemmSet s[3]; };

__global__ __launch_bounds__(512, 4) void gemm3_kernel(Gemm3Args a) {
  const GemmSet s = a.s[blockIdx.y];
  int row0, col0;
  swz512(blockIdx.x, row0, col0);
  gemm_body<0>(s.A, s.Bw, s.bias, nullptr, s.C, nullptr, row0, col0, 1024, 1024);
}

__global__ __launch_bounds__(512, 4) void gemm_a_kernel(
    const bf16* __restrict__ A, const bf16* __restrict__ Bw,
    const float* __restrict__ bias, const float* __restrict__ qv,
    float* __restrict__ aout) {
  int row0, col0;
  swz512(blockIdx.x, row0, col0);
  gemm_body<1>(A, Bw, bias, qv, nullptr, aout, row0, col0, 1024, 1024);
}

// ---------------------------------------------------------------- attention (R4 exact)
// Swapped QK^T (lane-local softmax), double-buffered K/V staging with a single
// barrier per KV tile, defer-rescale (THR=8), setprio around MFMA clusters.
// grid: (B*H, S/64). 4 waves x 16 q-rows each. KV tiles of 64.
__global__ __launch_bounds__(256) void attn_kernel(
    const bf16* __restrict__ qp, const bf16* __restrict__ kp,
    const bf16* __restrict__ vp, bf16* __restrict__ xb, float* __restrict__ xf) {
  constexpr int S = 1024, D = 1024;
  __shared__ __attribute__((aligned(16))) bf16 Ks[8192];  // 2x [d/8][64 kv][8]
  __shared__ __attribute__((aligned(16))) bf16 Vs[8192];  // 2x [kv/4][d/16][4][16]
  __shared__ __attribute__((aligned(16))) bf16 Ps[4096];  // per-wave [16 q][64 kv swz]
  const int tid = threadIdx.x, wid = tid >> 6, lane = tid & 63;
  const int g = lane >> 4, lc = lane & 15;
  const int b = blockIdx.x >> 4, h = blockIdx.x & 15;
  const int q0 = blockIdx.y * 64;
  const size_t base = (size_t)b * S * D + (size_t)h * 64;

  // Q fragments, pre-scaled by 1/sqrt(DK)=0.125 (exact in bf16)
  bf16x8 qf[2];
  {
    const bf16* qrow = qp + base + (size_t)(q0 + wid * 16 + lc) * D;
    qf[0] = *(const bf16x8*)(qrow + g * 8);
    qf[1] = *(const bf16x8*)(qrow + 32 + g * 8);
#pragma unroll
    for (int j = 0; j < 8; ++j) {
      qf[0][j] = (bf16)((float)qf[0][j] * 0.125f);
      qf[1][j] = (bf16)((float)qf[1][j] * 0.125f);
    }
  }
  float m_s = -1e30f, l_s = 0.f;
  const f32x4 z4 = {0.f, 0.f, 0.f, 0.f};
  f32x4 ax[4];  // O^T: ax[m][r] = O[q=lc][d=16m+4g+r]
#pragma unroll
  for (int m = 0; m < 4; ++m) ax[m] = z4;

  // K staging (chunked [d/8][64][8]): linear dest, linear source
  const int c0 = tid, c1 = tid + 256;
  const bf16* gK0 = kp + base + (size_t)(c0 & 63) * D + (c0 >> 6) * 8;
  const bf16* gK1 = kp + base + (size_t)(c1 & 63) * D + (c1 >> 6) * 8;
  bf16* lK0 = Ks + (size_t)(c0 - lane) * 8;
  bf16* lK1 = Ks + (size_t)(c1 - lane) * 8;
  // V staging: linear LDS dest = subtile slot E8; global source pre-swizzled
  const bf16* gV0 = vp + base + (size_t)((c0 >> 5) * 4 + ((c0 >> 1) & 3)) * D +
                    ((c0 >> 3) & 3) * 16 + (c0 & 1) * 8;
  const bf16* gV1 = vp + base + (size_t)((c1 >> 5) * 4 + ((c1 >> 1) & 3)) * D +
                    ((c1 >> 3) & 3) * 16 + (c1 & 1) * 8;
  bf16* lV0 = Vs + (size_t)(c0 - lane) * 8;
  bf16* lV1 = Vs + (size_t)(c1 - lane) * 8;

  bf16* pw = Ps + wid * 1024;
  const int pswz_a = lc & 3, pswz_b = (lc >> 2) & 3;
  const unsigned vaddr0 =
      (unsigned)(uintptr_t)(const __attribute__((address_space(3))) bf16*)(Vs + 512 * g + 4 * lc);

  // prologue: stage KV tile 0 into buffer 0
  GLDS16(gK0, lK0);
  GLDS16(gK1, lK1);
  GLDS16(gV0, lV0);
  GLDS16(gV1, lV1);

  for (int t = 0; t < 16; ++t) {
    __syncthreads();  // implicit vmcnt(0): tile t's loads landed (prefetched a
                      // full tile ago); separates t-1 reads from t+1 writes
    const int cur = t & 1;
    if (t < 15) {
      const size_t off = (size_t)(t + 1) * 64 * D;
      const int nb = cur ^ 1;
      GLDS16(gK0 + off, lK0 + nb * 4096);
      GLDS16(gK1 + off, lK1 + nb * 4096);
      GLDS16(gV0 + off, lV0 + nb * 4096);
      GLDS16(gV1 + off, lV1 + nb * 4096);
    }
    const bf16* Kb = Ks + cur * 4096;
    const unsigned va = vaddr0 + cur * 8192u;

    // S^T = K Q^T: sc[m][r] = S[q=lc][kv=16m+4g+r] (scale folded into qf)
    f32x4 sc[4];
    __builtin_amdgcn_s_setprio(1);
#pragma unroll
    for (int m = 0; m < 4; ++m) {
      f32x4 z = z4;
      bf16x8 kf0 = *(const bf16x8*)(Kb + (size_t)g * 512 + (m * 16 + lc) * 8);
      bf16x8 kf1 = *(const bf16x8*)(Kb + (size_t)(4 + g) * 512 + (m * 16 + lc) * 8);
      z = MFMA16(kf0, qf[0], z);
      z = MFMA16(kf1, qf[1], z);
      sc[m] = z;
    }
    __builtin_amdgcn_s_setprio(0);

    // online softmax with defer-rescale (THR=8)
    float mx = -1e30f;
#pragma unroll
    for (int m = 0; m < 4; ++m)
      mx = fmaxf(mx, fmaxf(fmaxf(sc[m][0], sc[m][1]), fmaxf(sc[m][2], sc[m][3])));
    mx = fmaxf(mx, __shfl_xor(mx, 16));
    mx = fmaxf(mx, __shfl_xor(mx, 32));
    if (!__all(mx - m_s <= 8.f)) {
      const float mn = fmaxf(m_s, mx);
      const float cr = __expf(m_s - mn);
      l_s *= cr;
#pragma unroll
      for (int m = 0; m < 4; ++m) ax[m] *= cr;
      m_s = mn;
    }
    float sm = 0.f;
#pragma unroll
    for (int m = 0; m < 4; ++m)
#pragma unroll
      for (int r = 0; r < 4; ++r) {
        float p = __expf(sc[m][r] - m_s);
        sc[m][r] = p;
        sm += p;
      }
    sm += __shfl_xor(sm, 16);
    sm += __shfl_xor(sm, 32);
    l_s += sm;

    // P -> bf16, packed b64 writes into swizzled per-wave buffer
#pragma unroll
    for (int m = 0; m < 4; ++m) {
      bf16x4 pk;
      pk[0] = (bf16)sc[m][0]; pk[1] = (bf16)sc[m][1];
      pk[2] = (bf16)sc[m][2]; pk[3] = (bf16)sc[m][3];
      *(bf16x4*)(pw + lc * 64 + 16 * (m ^ pswz_a) + 4 * (g ^ pswz_b)) = pk;
    }

    // P fragments (B operand): lane needs P[q=lc][kv=32kk+8g+4jh+r]
    bf16x4 pr[2][2];
#pragma unroll
    for (int kk = 0; kk < 2; ++kk)
#pragma unroll
      for (int jh = 0; jh < 2; ++jh) {
        const int msrc = 2 * kk + (g >> 1);
        const int gsrc = (2 * g + jh) & 3;
        pr[kk][jh] = *(const bf16x4*)(pw + lc * 64 + 16 * (msrc ^ pswz_a) + 4 * (gsrc ^ pswz_b));
      }
    bf16x8 pf0 = __builtin_shufflevector(pr[0][0], pr[0][1], 0, 1, 2, 3, 4, 5, 6, 7);
    bf16x8 pf1 = __builtin_shufflevector(pr[1][0], pr[1][1], 0, 1, 2, 3, 4, 5, 6, 7);

    // V^T fragments (A operand) via HW transpose reads
    bf16x4 vt[4][2][2];  // [md][kk][jh]
    TR16(vt[0][0][0], va, 0);    TR16(vt[1][0][0], va, 128);
    TR16(vt[2][0][0], va, 256);  TR16(vt[3][0][0], va, 384);
    TR16(vt[0][0][1], va, 512);  TR16(vt[1][0][1], va, 640);
    TR16(vt[2][0][1], va, 768);  TR16(vt[3][0][1], va, 896);
    TR16(vt[0][1][0], va, 4096); TR16(vt[1][1][0], va, 4224);
    TR16(vt[2][1][0], va, 4352); TR16(vt[3][1][0], va, 4480);
    TR16(vt[0][1][1], va, 4608); TR16(vt[1][1][1], va, 4736);
    TR16(vt[2][1][1], va, 4864); TR16(vt[3][1][1], va, 4992);
    asm volatile("s_waitcnt lgkmcnt(0)" ::: "memory");
    __builtin_amdgcn_sched_barrier(0);

    // O^T += V^T P^T
    __builtin_amdgcn_s_setprio(1);
#pragma unroll
    for (int md = 0; md < 4; ++md) {
      bf16x8 a0 = __builtin_shufflevector(vt[md][0][0], vt[md][0][1], 0, 1, 2, 3, 4, 5, 6, 7);
      bf16x8 a1 = __builtin_shufflevector(vt[md][1][0], vt[md][1][1], 0, 1, 2, 3, 4, 5, 6, 7);
      ax[md] = MFMA16(a0, pf0, ax[md]);
      ax[md] = MFMA16(a1, pf1, ax[md]);
    }
    __builtin_amdgcn_s_setprio(0);
  }

  // normalize + store x (bf16 for Wa-GEMM, f32 for final pooling), packed
  const float inv = 1.0f / l_s;
  const int qrow = q0 + wid * 16 + lc;
  float* xfr = xf + base + (size_t)qrow * D;
  bf16* xbr = xb + base + (size_t)qrow * D;
#pragma unroll
  for (int m = 0; m < 4; ++m) {
    f32x4 vv = ax[m] * inv;
    *(f32x4*)(xfr + 16 * m + 4 * g) = vv;
    bf16x4 bb;
    bb[0] = (bf16)vv[0]; bb[1] = (bf16)vv[1];
    bb[2] = (bf16)vv[2]; bb[3] = (bf16)vv[3];
    *(bf16x4*)(xbr + 16 * m + 4 * g) = bb;
  }
}

// ---------------------------------------------------------------- alpha softmax
__global__ __launch_bounds__(256) void softmax_rows(const float* __restrict__ av,
                                                    float* __restrict__ alpha) {
  const int b = blockIdx.x, t = threadIdx.x;
  __shared__ float red[8];
  f32x4 v = *(const f32x4*)(av + b * 1024 + t * 4);
  float m = fmaxf(fmaxf(v[0], v[1]), fmaxf(v[2], v[3]));
#pragma unroll
  for (int o = 1; o < 64; o <<= 1) m = fmaxf(m, __shfl_xor(m, o));
  if ((t & 63) == 0) red[t >> 6] = m;
  __syncthreads();
  m = fmaxf(fmaxf(red[0], red[1]), fmaxf(red[2], red[3]));
  f32x4 e;
  float s = 0.f;
#pragma unroll
  for (int j = 0; j < 4; ++j) { e[j] = __expf(v[j] - m); s += e[j]; }
#pragma unroll
  for (int o = 1; o < 64; o <<= 1) s += __shfl_xor(s, o);
  if ((t & 63) == 0) red[4 + (t >> 6)] = s;
  __syncthreads();
  const float inv = 1.0f / (red[4] + red[5] + red[6] + red[7]);
  *(f32x4*)(alpha + b * 1024 + t * 4) = e * inv;
}

// ---------------------------------------------------------------- pooling
__global__ __launch_bounds__(256) void pool_kernel(const float* __restrict__ xf,
                                                   const float* __restrict__ alpha,
                                                   float* __restrict__ out) {
  const int b = blockIdx.y, sc = blockIdx.x, t = threadIdx.x;
  f32x4 acc = {0.f, 0.f, 0.f, 0.f};
  const float* xrow = xf + (size_t)b * 1024 * 1024;
  for (int s = sc * 64; s < sc * 64 + 64; ++s) {
    const float al = alpha[b * 1024 + s];
    f32x4 xv = *(const f32x4*)(xrow + (size_t)s * 1024 + t * 4);
    acc += xv * al;
  }
  atomicAdd(&out[b * 1024 + t * 4 + 0], acc[0]);
  atomicAdd(&out[b * 1024 + t * 4 + 1], acc[1]);
  atomicAdd(&out[b * 1024 + t * 4 + 2], acc[2]);
  atomicAdd(&out[b * 1024 + t * 4 + 3], acc[3]);
}

// ---------------------------------------------------------------- launch
extern "C" void kernel_launch(void* const* d_in, const int* in_sizes, int n_in,
                              void* d_out, int out_size, void* d_ws, size_t ws_size,
                              hipStream_t stream) {
  const float* Q   = (const float*)d_in[0];
  const float* K   = (const float*)d_in[1];
  const float* V   = (const float*)d_in[2];
  const float* Wq  = (const float*)d_in[3];
  const float* bq  = (const float*)d_in[4];
  const float* Wk  = (const float*)d_in[5];
  const float* bk  = (const float*)d_in[6];
  const float* Wv  = (const float*)d_in[7];
  const float* bv  = (const float*)d_in[8];
  const float* Wa  = (const float*)d_in[9];
  const float* ba  = (const float*)d_in[10];
  const float* qvec = (const float*)d_in[11];
  float* out = (float*)d_out;
  char* ws = (char*)d_ws;
  const size_t MB = 1ull << 20;

  bf16* Wqb = (bf16*)(ws + 0 * MB);
  bf16* Wkb = (bf16*)(ws + 2 * MB);
  bf16* Wvb = (bf16*)(ws + 4 * MB);
  bf16* Wab = (bf16*)(ws + 6 * MB);
  bf16* qb  = (bf16*)(ws + 8 * MB);
  bf16* kb  = (bf16*)(ws + 24 * MB);
  bf16* vb  = (bf16*)(ws + 40 * MB);
  bf16* qp  = (bf16*)(ws + 56 * MB);
  bf16* kp  = (bf16*)(ws + 72 * MB);
  bf16* vp  = (bf16*)(ws + 88 * MB);
  float* av    = (float*)(ws + 104 * MB);
  float* alpha = (float*)(ws + 104 * MB + 65536);
  bf16* xb  = qb;                       // qb dead after Q projection
  float* xf = (float*)(ws + 24 * MB);   // kb+vb dead after K/V projections

  // accumulator zeroing up front
  hipMemsetAsync(av, 0, 8192 * sizeof(float), stream);
  hipMemsetAsync(out, 0, 8192 * sizeof(float), stream);

  // f32 -> bf16 conversions: 2 fused dispatches
  CvtArgs cq = {{Q, K, V, nullptr}, {qb, kb, vb, nullptr}};
  f2b_multi<<<dim3(4096, 3), 256, 0, stream>>>(cq, 1048576);
  CvtArgs cw = {{Wq, Wk, Wv, Wa}, {Wqb, Wkb, Wvb, Wab}};
  f2b_multi<<<dim3(512, 4), 256, 0, stream>>>(cw, 131072);

  // projections: one dispatch, y = {q,k,v}; 512 swizzled blocks per GEMM
  Gemm3Args g3 = {{{qb, Wqb, bq, qp}, {kb, Wkb, bk, kp}, {vb, Wvb, bv, vp}}};
  gemm3_kernel<<<dim3(512, 3), 512, 0, stream>>>(g3);

  // flash attention
  attn_kernel<<<dim3(128, 16), 256, 0, stream>>>(qp, kp, vp, xb, xf);

  // pooling head: a[m] = sum_n tanh(x Wa^T + ba)*qvec
  gemm_a_kernel<<<512, 512, 0, stream>>>(xb, Wab, ba, qvec, av);

  softmax_rows<<<8, 256, 0, stream>>>(av, alpha);
  pool_kernel<<<dim3(16, 8), 256, 0, stream>>>(xf, alpha, out);
}